// Round 1
// baseline (3296.973 us; speedup 1.0000x reference)
//
#include <hip/hip_runtime.h>

#define NF 96
#define NC4 24   // NF / 4 float4 chunks per row

// ---------------- init: deg=1 (self-loop), zero pool sums/cnt ----------------
__global__ __launch_bounds__(256) void k_init(float* __restrict__ deg,
                                              float* __restrict__ sums,
                                              float* __restrict__ cnt,
                                              int n, int nseg) {
    int i = blockIdx.x * 256 + threadIdx.x;
    if (i < n) deg[i] = 1.0f;                 // self-loop weight 1
    if (i < nseg * NF) sums[i] = 0.0f;
    if (i < nseg) cnt[i] = 0.0f;
}

// ---------------- deg[dst] += w ----------------
__global__ __launch_bounds__(256) void k_deg(const int* __restrict__ dst,
                                             const float* __restrict__ w,
                                             float* __restrict__ deg, int E) {
    int e = blockIdx.x * 256 + threadIdx.x;
    if (e < E) atomicAdd(&deg[dst[e]], w[e]);
}

// ---------------- deg -> deg^{-1/2} in place ----------------
__global__ __launch_bounds__(256) void k_dis(float* __restrict__ deg, int n) {
    int i = blockIdx.x * 256 + threadIdx.x;
    if (i < n) {
        float d = deg[i];
        deg[i] = (d > 0.0f) ? rsqrtf(d) : 0.0f;
    }
}

// ---------------- norm[e] = dis[src]*w*dis[dst] (shared by all 3 layers) ----
__global__ __launch_bounds__(256) void k_norm(const int* __restrict__ src,
                                              const int* __restrict__ dst,
                                              const float* __restrict__ w,
                                              const float* __restrict__ dis,
                                              float* __restrict__ norm, int E) {
    int e = blockIdx.x * 256 + threadIdx.x;
    if (e < E) norm[e] = dis[src[e]] * w[e] * dis[dst[e]];
}

// ---------------- xw = act(A) @ W   (A:[n,96], W:[96,96]) ----------------
// 32 rows per block; W staged in LDS (36 KB) + A tile in LDS (12 KB).
__global__ __launch_bounds__(256) void k_gemm(const float* __restrict__ A,
                                              const float* __restrict__ W,
                                              float* __restrict__ out,
                                              int n, int relu_in) {
    __shared__ float sW[NF * NF];
    __shared__ float sA[32 * NF];
    const int tid = threadIdx.x;

    for (int i = tid; i < NF * NF; i += 256) sW[i] = W[i];

    const int row0 = blockIdx.x * 32;
    const int nrows = min(32, n - row0);

    const float4* A4 = (const float4*)A;
    float4* sA4 = (float4*)sA;
    #pragma unroll
    for (int t = 0; t < 3; ++t) {
        int id = tid + 256 * t;            // 0..767 = 32 rows * 24 chunks
        int r = id / NC4, c = id % NC4;
        if (r < nrows) {
            float4 v = A4[(size_t)(row0 + r) * NC4 + c];
            if (relu_in) {
                v.x = fmaxf(v.x, 0.0f); v.y = fmaxf(v.y, 0.0f);
                v.z = fmaxf(v.z, 0.0f); v.w = fmaxf(v.w, 0.0f);
            }
            sA4[id] = v;
        }
    }
    __syncthreads();

    const float4* sW4 = (const float4*)sW;
    float4* O4 = (float4*)out;
    #pragma unroll
    for (int t = 0; t < 3; ++t) {
        int id = tid + 256 * t;
        int r = id / NC4, c = id % NC4;
        if (r >= nrows) continue;
        float4 acc = make_float4(0.f, 0.f, 0.f, 0.f);
        #pragma unroll 8
        for (int k = 0; k < NF; ++k) {
            float a = sA[r * NF + k];
            float4 wv = sW4[k * NC4 + c];
            acc.x += a * wv.x; acc.y += a * wv.y;
            acc.z += a * wv.z; acc.w += a * wv.w;
        }
        O4[(size_t)(row0 + r) * NC4 + c] = acc;
    }
}

// ---------------- out[i] = dis[i]^2 * xw[i] + b  (self-loop + bias init) ----
__global__ __launch_bounds__(256) void k_selfloop(const float* __restrict__ xw,
                                                  const float* __restrict__ dis,
                                                  const float* __restrict__ b,
                                                  float* __restrict__ out, int n) {
    int idx = blockIdx.x * 256 + threadIdx.x;   // over n * NC4
    if (idx >= n * NC4) return;
    int i = idx / NC4, c = idx % NC4;
    float dd = dis[i];
    dd *= dd;
    float4 v = ((const float4*)xw)[idx];
    float4 bb = ((const float4*)b)[c];
    float4 o;
    o.x = dd * v.x + bb.x;
    o.y = dd * v.y + bb.y;
    o.z = dd * v.z + bb.z;
    o.w = dd * v.w + bb.w;
    ((float4*)out)[idx] = o;
}

// ---------------- out[dst] += norm[e] * xw[src]  (edge scatter) ----------------
// 24 threads per edge, one float4 chunk each.
__global__ __launch_bounds__(256) void k_edge(const float* __restrict__ xw,
                                              const int* __restrict__ src,
                                              const int* __restrict__ dst,
                                              const float* __restrict__ norm,
                                              float* __restrict__ out, int E) {
    int idx = blockIdx.x * 256 + threadIdx.x;   // over E * NC4
    if (idx >= E * NC4) return;
    int e = idx / NC4, c = idx % NC4;
    int s = src[e], d = dst[e];
    float coef = norm[e];
    float4 v = ((const float4*)(xw + (size_t)s * NF))[c];
    float* o = out + (size_t)d * NF + c * 4;
    atomicAdd(o + 0, coef * v.x);
    atomicAdd(o + 1, coef * v.y);
    atomicAdd(o + 2, coef * v.z);
    atomicAdd(o + 3, coef * v.w);
}

// ---------------- pooling scatter: sums[batch[i]] += h[i]; cnt[batch[i]]++ ----
__global__ __launch_bounds__(256) void k_pool(const float* __restrict__ h,
                                              const int* __restrict__ batch,
                                              float* __restrict__ sums,
                                              float* __restrict__ cnt, int n) {
    int idx = blockIdx.x * 256 + threadIdx.x;   // over n * NC4
    if (idx >= n * NC4) return;
    int i = idx / NC4, c = idx % NC4;
    int g = batch[i];
    float4 v = ((const float4*)h)[idx];
    float* s = sums + (size_t)g * NF + c * 4;
    atomicAdd(s + 0, v.x);
    atomicAdd(s + 1, v.y);
    atomicAdd(s + 2, v.z);
    atomicAdd(s + 3, v.w);
    if (c == 0) atomicAdd(&cnt[g], 1.0f);
}

// ---------------- final: out[g][c] = (sums[g]/max(cnt,1)) . Wl[:,c] + bl[c] ----
__global__ __launch_bounds__(256) void k_final(const float* __restrict__ sums,
                                               const float* __restrict__ cnt,
                                               const float* __restrict__ Wl,
                                               const float* __restrict__ bl,
                                               float* __restrict__ out,
                                               int ngraphs, int ncls) {
    int idx = blockIdx.x * 256 + threadIdx.x;
    if (idx >= ngraphs * ncls) return;
    int g = idx / ncls, c = idx % ncls;
    float inv = 1.0f / fmaxf(cnt[g], 1.0f);
    float acc = 0.0f;
    for (int f = 0; f < NF; ++f)
        acc += sums[(size_t)g * NF + f] * Wl[f * ncls + c];
    out[idx] = acc * inv + bl[c];
}

extern "C" void kernel_launch(void* const* d_in, const int* in_sizes, int n_in,
                              void* d_out, int out_size, void* d_ws, size_t ws_size,
                              hipStream_t stream) {
    const float* x  = (const float*)d_in[0];
    const float* ew = (const float*)d_in[1];
    const float* W1 = (const float*)d_in[2];
    const float* b1 = (const float*)d_in[3];
    const float* W2 = (const float*)d_in[4];
    const float* b2 = (const float*)d_in[5];
    const float* W3 = (const float*)d_in[6];
    const float* b3 = (const float*)d_in[7];
    const float* Wl = (const float*)d_in[8];
    const float* bl = (const float*)d_in[9];
    const int* ei    = (const int*)d_in[10];
    const int* batch = (const int*)d_in[11];

    const int n = in_sizes[0] / NF;            // 50000
    const int E = in_sizes[1];                 // 800000
    const int ncls = 10;
    const int ngraphs = out_size / ncls;       // 512
    const int* src = ei;
    const int* dst = ei + E;

    // workspace layout (all float, offsets are multiples of 4 floats)
    float* ws   = (float*)d_ws;
    float* dis  = ws;                            // n        (deg -> dis in place)
    float* sums = dis + n;                       // ngraphs*NF
    float* cnt  = sums + (size_t)ngraphs * NF;   // ngraphs
    float* norm = cnt + ngraphs;                 // E
    float* bufA = norm + E;                      // n*NF   (h buffer)
    float* bufB = bufA + (size_t)n * NF;         // n*NF   (xw buffer)

    const int T = 256;
    int gInit = (max(n, ngraphs * NF) + T - 1) / T;
    int gN    = (n + T - 1) / T;
    int gE    = (E + T - 1) / T;
    int gN24  = (n * NC4 + T - 1) / T;
    int gE24  = (int)(((size_t)E * NC4 + T - 1) / T);
    int gGemm = (n + 31) / 32;

    // degree / normalization (identical for all 3 layers)
    k_init<<<gInit, T, 0, stream>>>(dis, sums, cnt, n, ngraphs);
    k_deg<<<gE, T, 0, stream>>>(dst, ew, dis, E);
    k_dis<<<gN, T, 0, stream>>>(dis, n);
    k_norm<<<gE, T, 0, stream>>>(src, dst, ew, dis, norm, E);

    // layer 1: x -> bufB (xw) -> bufA (h1 = aggr + b1)
    k_gemm<<<gGemm, T, 0, stream>>>(x, W1, bufB, n, 0);
    k_selfloop<<<gN24, T, 0, stream>>>(bufB, dis, b1, bufA, n);
    k_edge<<<gE24, T, 0, stream>>>(bufB, src, dst, norm, bufA, E);

    // layer 2: relu(bufA) -> bufB -> bufA
    k_gemm<<<gGemm, T, 0, stream>>>(bufA, W2, bufB, n, 1);
    k_selfloop<<<gN24, T, 0, stream>>>(bufB, dis, b2, bufA, n);
    k_edge<<<gE24, T, 0, stream>>>(bufB, src, dst, norm, bufA, E);

    // layer 3: relu(bufA) -> bufB -> bufA (no relu after)
    k_gemm<<<gGemm, T, 0, stream>>>(bufA, W3, bufB, n, 1);
    k_selfloop<<<gN24, T, 0, stream>>>(bufB, dis, b3, bufA, n);
    k_edge<<<gE24, T, 0, stream>>>(bufB, src, dst, norm, bufA, E);

    // mean-pool + classifier head
    k_pool<<<gN24, T, 0, stream>>>(bufA, batch, sums, cnt, n);
    k_final<<<(ngraphs * ncls + T - 1) / T, T, 0, stream>>>(
        sums, cnt, Wl, bl, (float*)d_out, ngraphs, ncls);
}

// Round 2
// 517.026 us; speedup vs baseline: 6.3768x; 6.3768x over previous
//
#include <hip/hip_runtime.h>

#define NF 96
#define NC4 24   // NF / 4 float4 chunks per row

// ---------------- init: deg=1 (self-loop), hist=0, zero pool sums/cnt --------
__global__ __launch_bounds__(256) void k_init(float* __restrict__ deg,
                                              int* __restrict__ hist,
                                              float* __restrict__ sums,
                                              float* __restrict__ cnt,
                                              int n, int nseg) {
    int i = blockIdx.x * 256 + threadIdx.x;
    if (i < n) { deg[i] = 1.0f; hist[i] = 0; }
    if (i < nseg * NF) sums[i] = 0.0f;
    if (i < nseg) cnt[i] = 0.0f;
}

// ---------------- deg[dst] += w ; hist[dst]++ ----------------
__global__ __launch_bounds__(256) void k_deg_hist(const int* __restrict__ dst,
                                                  const float* __restrict__ w,
                                                  float* __restrict__ deg,
                                                  int* __restrict__ hist, int E) {
    int e = blockIdx.x * 256 + threadIdx.x;
    if (e < E) {
        int d = dst[e];
        atomicAdd(&deg[d], w[e]);
        atomicAdd(&hist[d], 1);
    }
}

// ---------------- deg -> deg^{-1/2} in place ----------------
__global__ __launch_bounds__(256) void k_dis(float* __restrict__ deg, int n) {
    int i = blockIdx.x * 256 + threadIdx.x;
    if (i < n) {
        float d = deg[i];
        deg[i] = (d > 0.0f) ? rsqrtf(d) : 0.0f;
    }
}

// ---------------- scan pass 1: per-block inclusive scan of hist ----------------
__global__ __launch_bounds__(256) void k_scan1(const int* __restrict__ hist,
                                               int* __restrict__ tmp,
                                               int* __restrict__ blksum, int n) {
    __shared__ int s[256];
    int t = threadIdx.x;
    int i = blockIdx.x * 256 + t;
    int v = (i < n) ? hist[i] : 0;
    s[t] = v;
    __syncthreads();
    #pragma unroll
    for (int off = 1; off < 256; off <<= 1) {
        int x = (t >= off) ? s[t - off] : 0;
        __syncthreads();
        s[t] += x;
        __syncthreads();
    }
    if (i < n) tmp[i] = s[t];
    if (t == 255) blksum[blockIdx.x] = s[t];
}

// ---------------- scan pass 2: exclusive scan of block sums (1 block) --------
__global__ __launch_bounds__(256) void k_scan2(const int* __restrict__ blksum,
                                               int* __restrict__ blkoff, int nb) {
    __shared__ int s[256];
    int t = threadIdx.x;
    int v = (t < nb) ? blksum[t] : 0;
    s[t] = v;
    __syncthreads();
    #pragma unroll
    for (int off = 1; off < 256; off <<= 1) {
        int x = (t >= off) ? s[t - off] : 0;
        __syncthreads();
        s[t] += x;
        __syncthreads();
    }
    if (t < nb) blkoff[t] = s[t] - v;   // exclusive
}

// ---------------- scan pass 3: rowstart[i+1] = tmp[i]+blkoff; hist -> cursor 0 ----
__global__ __launch_bounds__(256) void k_scan3(const int* __restrict__ tmp,
                                               const int* __restrict__ blkoff,
                                               int* __restrict__ rowstart,
                                               int* __restrict__ hist, int n) {
    int i = blockIdx.x * 256 + threadIdx.x;
    if (i < n) {
        rowstart[i + 1] = tmp[i] + blkoff[blockIdx.x];
        hist[i] = 0;                    // becomes the scatter cursor
        if (i == 0) rowstart[0] = 0;
    }
}

// ---------------- scatter edges into CSR slots: epack = (src, norm) ----------
__global__ __launch_bounds__(256) void k_scatter(const int* __restrict__ src,
                                                 const int* __restrict__ dst,
                                                 const float* __restrict__ w,
                                                 const float* __restrict__ dis,
                                                 const int* __restrict__ rowstart,
                                                 int* __restrict__ cursor,
                                                 float2* __restrict__ epack, int E) {
    int e = blockIdx.x * 256 + threadIdx.x;
    if (e < E) {
        int s = src[e], d = dst[e];
        int slot = rowstart[d] + atomicAdd(&cursor[d], 1);
        float nrm = dis[s] * w[e] * dis[d];
        epack[slot] = make_float2(__int_as_float(s), nrm);
    }
}

// ---------------- xw = act(A) @ W   (A:[n,96], W:[96,96]) ----------------
__global__ __launch_bounds__(256) void k_gemm(const float* __restrict__ A,
                                              const float* __restrict__ W,
                                              float* __restrict__ out,
                                              int n, int relu_in) {
    __shared__ float sW[NF * NF];
    __shared__ float sA[32 * NF];
    const int tid = threadIdx.x;

    for (int i = tid; i < NF * NF; i += 256) sW[i] = W[i];

    const int row0 = blockIdx.x * 32;
    const int nrows = min(32, n - row0);

    const float4* A4 = (const float4*)A;
    float4* sA4 = (float4*)sA;
    #pragma unroll
    for (int t = 0; t < 3; ++t) {
        int id = tid + 256 * t;            // 0..767 = 32 rows * 24 chunks
        int r = id / NC4, c = id % NC4;
        if (r < nrows) {
            float4 v = A4[(size_t)(row0 + r) * NC4 + c];
            if (relu_in) {
                v.x = fmaxf(v.x, 0.0f); v.y = fmaxf(v.y, 0.0f);
                v.z = fmaxf(v.z, 0.0f); v.w = fmaxf(v.w, 0.0f);
            }
            sA4[id] = v;
        }
    }
    __syncthreads();

    const float4* sW4 = (const float4*)sW;
    float4* O4 = (float4*)out;
    #pragma unroll
    for (int t = 0; t < 3; ++t) {
        int id = tid + 256 * t;
        int r = id / NC4, c = id % NC4;
        if (r >= nrows) continue;
        float4 acc = make_float4(0.f, 0.f, 0.f, 0.f);
        #pragma unroll 8
        for (int k = 0; k < NF; ++k) {
            float a = sA[r * NF + k];
            float4 wv = sW4[k * NC4 + c];
            acc.x += a * wv.x; acc.y += a * wv.y;
            acc.z += a * wv.z; acc.w += a * wv.w;
        }
        O4[(size_t)(row0 + r) * NC4 + c] = acc;
    }
}

// ---------------- gather: out[i] = b + dis[i]^2*xw[i] + sum_j norm_j*xw[src_j] ----
__global__ __launch_bounds__(256) void k_gather(const float* __restrict__ xw,
                                                const float2* __restrict__ epack,
                                                const int* __restrict__ rowstart,
                                                const float* __restrict__ dis,
                                                const float* __restrict__ b,
                                                float* __restrict__ out, int n) {
    int idx = blockIdx.x * 256 + threadIdx.x;   // over n * NC4
    if (idx >= n * NC4) return;
    int i = idx / NC4, c = idx % NC4;
    const float4* xw4 = (const float4*)xw;

    float dd = dis[i];
    dd *= dd;
    float4 v = xw4[(size_t)i * NC4 + c];
    float4 bb = ((const float4*)b)[c];
    float4 acc;
    acc.x = dd * v.x + bb.x;
    acc.y = dd * v.y + bb.y;
    acc.z = dd * v.z + bb.z;
    acc.w = dd * v.w + bb.w;

    int j0 = rowstart[i], j1 = rowstart[i + 1];
    for (int j = j0; j < j1; ++j) {
        float2 ep = epack[j];
        int s = __float_as_int(ep.x);
        float coef = ep.y;
        float4 sv = xw4[(size_t)s * NC4 + c];
        acc.x += coef * sv.x;
        acc.y += coef * sv.y;
        acc.z += coef * sv.z;
        acc.w += coef * sv.w;
    }
    ((float4*)out)[idx] = acc;
}

// ---------------- pooling scatter: sums[batch[i]] += h[i]; cnt[batch[i]]++ ----
__global__ __launch_bounds__(256) void k_pool(const float* __restrict__ h,
                                              const int* __restrict__ batch,
                                              float* __restrict__ sums,
                                              float* __restrict__ cnt, int n) {
    int idx = blockIdx.x * 256 + threadIdx.x;   // over n * NC4
    if (idx >= n * NC4) return;
    int i = idx / NC4, c = idx % NC4;
    int g = batch[i];
    float4 v = ((const float4*)h)[idx];
    float* s = sums + (size_t)g * NF + c * 4;
    atomicAdd(s + 0, v.x);
    atomicAdd(s + 1, v.y);
    atomicAdd(s + 2, v.z);
    atomicAdd(s + 3, v.w);
    if (c == 0) atomicAdd(&cnt[g], 1.0f);
}

// ---------------- final: out[g][c] = (sums[g]/max(cnt,1)) . Wl[:,c] + bl[c] ----
__global__ __launch_bounds__(256) void k_final(const float* __restrict__ sums,
                                               const float* __restrict__ cnt,
                                               const float* __restrict__ Wl,
                                               const float* __restrict__ bl,
                                               float* __restrict__ out,
                                               int ngraphs, int ncls) {
    int idx = blockIdx.x * 256 + threadIdx.x;
    if (idx >= ngraphs * ncls) return;
    int g = idx / ncls, c = idx % ncls;
    float inv = 1.0f / fmaxf(cnt[g], 1.0f);
    float acc = 0.0f;
    for (int f = 0; f < NF; ++f)
        acc += sums[(size_t)g * NF + f] * Wl[f * ncls + c];
    out[idx] = acc * inv + bl[c];
}

extern "C" void kernel_launch(void* const* d_in, const int* in_sizes, int n_in,
                              void* d_out, int out_size, void* d_ws, size_t ws_size,
                              hipStream_t stream) {
    const float* x  = (const float*)d_in[0];
    const float* ew = (const float*)d_in[1];
    const float* W1 = (const float*)d_in[2];
    const float* b1 = (const float*)d_in[3];
    const float* W2 = (const float*)d_in[4];
    const float* b2 = (const float*)d_in[5];
    const float* W3 = (const float*)d_in[6];
    const float* b3 = (const float*)d_in[7];
    const float* Wl = (const float*)d_in[8];
    const float* bl = (const float*)d_in[9];
    const int* ei    = (const int*)d_in[10];
    const int* batch = (const int*)d_in[11];

    const int n = in_sizes[0] / NF;            // 50000
    const int E = in_sizes[1];                 // 800000
    const int ncls = 10;
    const int ngraphs = out_size / ncls;       // 512
    const int* src = ei;
    const int* dst = ei + E;

    // ---- workspace layout ----
    char* p = (char*)d_ws;
    float2* epack  = (float2*)p;            p += (size_t)E * sizeof(float2);
    float* bufA    = (float*)p;             p += (size_t)n * NF * sizeof(float);
    float* bufB    = (float*)p;             p += (size_t)n * NF * sizeof(float);
    float* dis     = (float*)p;             p += (size_t)n * sizeof(float);
    float* sums    = (float*)p;             p += (size_t)ngraphs * NF * sizeof(float);
    float* cnt     = (float*)p;             p += (size_t)ngraphs * sizeof(float);
    int*   hist    = (int*)p;               p += (size_t)n * sizeof(int);
    int*   rowstart= (int*)p;               p += (size_t)(n + 1) * sizeof(int);
    int*   tmp     = (int*)p;               p += (size_t)n * sizeof(int);
    int*   blksum  = (int*)p;               p += 256 * sizeof(int);
    int*   blkoff  = (int*)p;               /* p += 256 * sizeof(int); */

    const int T = 256;
    int gInit = (max(n, ngraphs * NF) + T - 1) / T;
    int gN    = (n + T - 1) / T;       // also the scan block count (196 <= 256)
    int gE    = (E + T - 1) / T;
    int gN24  = (n * NC4 + T - 1) / T;
    int gGemm = (n + 31) / 32;

    // ---- build degree + CSR (once, reused by all 3 layers) ----
    k_init<<<gInit, T, 0, stream>>>(dis, hist, sums, cnt, n, ngraphs);
    k_deg_hist<<<gE, T, 0, stream>>>(dst, ew, dis, hist, E);
    k_dis<<<gN, T, 0, stream>>>(dis, n);
    k_scan1<<<gN, T, 0, stream>>>(hist, tmp, blksum, n);
    k_scan2<<<1, T, 0, stream>>>(blksum, blkoff, gN);
    k_scan3<<<gN, T, 0, stream>>>(tmp, blkoff, rowstart, hist, n);
    k_scatter<<<gE, T, 0, stream>>>(src, dst, ew, dis, rowstart, hist, epack, E);

    // ---- layer 1: x -> bufB (xw) -> bufA (h1) ----
    k_gemm<<<gGemm, T, 0, stream>>>(x, W1, bufB, n, 0);
    k_gather<<<gN24, T, 0, stream>>>(bufB, epack, rowstart, dis, b1, bufA, n);

    // ---- layer 2: relu(bufA) -> bufB -> bufA ----
    k_gemm<<<gGemm, T, 0, stream>>>(bufA, W2, bufB, n, 1);
    k_gather<<<gN24, T, 0, stream>>>(bufB, epack, rowstart, dis, b2, bufA, n);

    // ---- layer 3: relu(bufA) -> bufB -> bufA ----
    k_gemm<<<gGemm, T, 0, stream>>>(bufA, W3, bufB, n, 1);
    k_gather<<<gN24, T, 0, stream>>>(bufB, epack, rowstart, dis, b3, bufA, n);

    // ---- mean-pool + classifier head ----
    k_pool<<<gN24, T, 0, stream>>>(bufA, batch, sums, cnt, n);
    k_final<<<(ngraphs * ncls + T - 1) / T, T, 0, stream>>>(
        sums, cnt, Wl, bl, (float*)d_out, ngraphs, ncls);
}

// Round 3
// 398.786 us; speedup vs baseline: 8.2675x; 1.2965x over previous
//
#include <hip/hip_runtime.h>

#define NF 96
#define NC4 24   // NF / 4 float4 chunks per row

// ---------------- init: deg=1 (self-loop), hist=0 ----------------
__global__ __launch_bounds__(256) void k_init(float* __restrict__ deg,
                                              int* __restrict__ hist, int n) {
    int i = blockIdx.x * 256 + threadIdx.x;
    if (i < n) { deg[i] = 1.0f; hist[i] = 0; }
}

// ---------------- deg[dst] += w ; hist[dst]++ ----------------
__global__ __launch_bounds__(256) void k_deg_hist(const int* __restrict__ dst,
                                                  const float* __restrict__ w,
                                                  float* __restrict__ deg,
                                                  int* __restrict__ hist, int E) {
    int e = blockIdx.x * 256 + threadIdx.x;
    if (e < E) {
        int d = dst[e];
        atomicAdd(&deg[d], w[e]);
        atomicAdd(&hist[d], 1);
    }
}

// ---------------- deg -> deg^{-1/2} in place ----------------
__global__ __launch_bounds__(256) void k_dis(float* __restrict__ deg, int n) {
    int i = blockIdx.x * 256 + threadIdx.x;
    if (i < n) {
        float d = deg[i];
        deg[i] = (d > 0.0f) ? rsqrtf(d) : 0.0f;
    }
}

// ---------------- scan pass 1: per-block inclusive scan of hist ----------------
__global__ __launch_bounds__(256) void k_scan1(const int* __restrict__ hist,
                                               int* __restrict__ tmp,
                                               int* __restrict__ blksum, int n) {
    __shared__ int s[256];
    int t = threadIdx.x;
    int i = blockIdx.x * 256 + t;
    int v = (i < n) ? hist[i] : 0;
    s[t] = v;
    __syncthreads();
    #pragma unroll
    for (int off = 1; off < 256; off <<= 1) {
        int x = (t >= off) ? s[t - off] : 0;
        __syncthreads();
        s[t] += x;
        __syncthreads();
    }
    if (i < n) tmp[i] = s[t];
    if (t == 255) blksum[blockIdx.x] = s[t];
}

// ---------------- scan pass 2: exclusive scan of block sums (1 block) --------
__global__ __launch_bounds__(256) void k_scan2(const int* __restrict__ blksum,
                                               int* __restrict__ blkoff, int nb) {
    __shared__ int s[256];
    int t = threadIdx.x;
    int v = (t < nb) ? blksum[t] : 0;
    s[t] = v;
    __syncthreads();
    #pragma unroll
    for (int off = 1; off < 256; off <<= 1) {
        int x = (t >= off) ? s[t - off] : 0;
        __syncthreads();
        s[t] += x;
        __syncthreads();
    }
    if (t < nb) blkoff[t] = s[t] - v;   // exclusive
}

// ---------------- scan pass 3: rowstart[i+1] = tmp[i]+blkoff; hist -> cursor 0 ----
__global__ __launch_bounds__(256) void k_scan3(const int* __restrict__ tmp,
                                               const int* __restrict__ blkoff,
                                               int* __restrict__ rowstart,
                                               int* __restrict__ hist, int n) {
    int i = blockIdx.x * 256 + threadIdx.x;
    if (i < n) {
        rowstart[i + 1] = tmp[i] + blkoff[blockIdx.x];
        hist[i] = 0;                    // becomes the scatter cursor
        if (i == 0) rowstart[0] = 0;
    }
}

// ---------------- scatter edges into CSR slots: epack = (src, norm) ----------
__global__ __launch_bounds__(256) void k_scatter(const int* __restrict__ src,
                                                 const int* __restrict__ dst,
                                                 const float* __restrict__ w,
                                                 const float* __restrict__ dis,
                                                 const int* __restrict__ rowstart,
                                                 int* __restrict__ cursor,
                                                 float2* __restrict__ epack, int E) {
    int e = blockIdx.x * 256 + threadIdx.x;
    if (e < E) {
        int s = src[e], d = dst[e];
        int slot = rowstart[d] + atomicAdd(&cursor[d], 1);
        float nrm = dis[s] * w[e] * dis[d];
        epack[slot] = make_float2(__int_as_float(s), nrm);
    }
}

// ---------------- graph boundaries from sorted batch ----------------
__global__ __launch_bounds__(256) void k_bounds(const int* __restrict__ batch,
                                                int* __restrict__ gstart,
                                                int n, int ngraphs) {
    int i = blockIdx.x * 256 + threadIdx.x;
    if (i >= n) return;
    int b = batch[i];
    if (i == 0) {
        for (int g = 0; g <= b; ++g) gstart[g] = 0;
    } else {
        int pb = batch[i - 1];
        for (int g = pb + 1; g <= b; ++g) gstart[g] = i;
    }
    if (i == n - 1) {
        for (int g = b + 1; g <= ngraphs; ++g) gstart[g] = n;
    }
}

// ---------------- xw = act(A) @ W   (A:[n,96], W:[96,96]) ----------------
__global__ __launch_bounds__(256) void k_gemm(const float* __restrict__ A,
                                              const float* __restrict__ W,
                                              float* __restrict__ out,
                                              int n, int relu_in) {
    __shared__ float sW[NF * NF];
    __shared__ float sA[32 * NF];
    const int tid = threadIdx.x;

    for (int i = tid; i < NF * NF; i += 256) sW[i] = W[i];

    const int row0 = blockIdx.x * 32;
    const int nrows = min(32, n - row0);

    const float4* A4 = (const float4*)A;
    float4* sA4 = (float4*)sA;
    #pragma unroll
    for (int t = 0; t < 3; ++t) {
        int id = tid + 256 * t;            // 0..767 = 32 rows * 24 chunks
        int r = id / NC4, c = id % NC4;
        if (r < nrows) {
            float4 v = A4[(size_t)(row0 + r) * NC4 + c];
            if (relu_in) {
                v.x = fmaxf(v.x, 0.0f); v.y = fmaxf(v.y, 0.0f);
                v.z = fmaxf(v.z, 0.0f); v.w = fmaxf(v.w, 0.0f);
            }
            sA4[id] = v;
        }
    }
    __syncthreads();

    const float4* sW4 = (const float4*)sW;
    float4* O4 = (float4*)out;
    #pragma unroll
    for (int t = 0; t < 3; ++t) {
        int id = tid + 256 * t;
        int r = id / NC4, c = id % NC4;
        if (r >= nrows) continue;
        float4 acc = make_float4(0.f, 0.f, 0.f, 0.f);
        #pragma unroll 8
        for (int k = 0; k < NF; ++k) {
            float a = sA[r * NF + k];
            float4 wv = sW4[k * NC4 + c];
            acc.x += a * wv.x; acc.y += a * wv.y;
            acc.z += a * wv.z; acc.w += a * wv.w;
        }
        O4[(size_t)(row0 + r) * NC4 + c] = acc;
    }
}

// ---------------- gather: out[i] = b + dis[i]^2*xw[i] + sum_j norm_j*xw[src_j] ----
__global__ __launch_bounds__(256) void k_gather(const float* __restrict__ xw,
                                                const float2* __restrict__ epack,
                                                const int* __restrict__ rowstart,
                                                const float* __restrict__ dis,
                                                const float* __restrict__ b,
                                                float* __restrict__ out, int n) {
    int idx = blockIdx.x * 256 + threadIdx.x;   // over n * NC4
    if (idx >= n * NC4) return;
    int i = idx / NC4, c = idx % NC4;
    const float4* xw4 = (const float4*)xw;

    float dd = dis[i];
    dd *= dd;
    float4 v = xw4[(size_t)i * NC4 + c];
    float4 bb = ((const float4*)b)[c];
    float4 acc;
    acc.x = dd * v.x + bb.x;
    acc.y = dd * v.y + bb.y;
    acc.z = dd * v.z + bb.z;
    acc.w = dd * v.w + bb.w;

    int j0 = rowstart[i], j1 = rowstart[i + 1];
    for (int j = j0; j < j1; ++j) {
        float2 ep = epack[j];
        int s = __float_as_int(ep.x);
        float coef = ep.y;
        float4 sv = xw4[(size_t)s * NC4 + c];
        acc.x += coef * sv.x;
        acc.y += coef * sv.y;
        acc.z += coef * sv.z;
        acc.w += coef * sv.w;
    }
    ((float4*)out)[idx] = acc;
}

// ---------------- fused mean-pool + classifier head ----------------
// one block per graph; 192 active threads = 8 row-groups x 24 chunks.
__global__ __launch_bounds__(256) void k_poolfinal(const float* __restrict__ h,
                                                   const int* __restrict__ gstart,
                                                   const float* __restrict__ Wl,
                                                   const float* __restrict__ bl,
                                                   float* __restrict__ out, int ncls) {
    __shared__ float red[8][NF];
    __shared__ float pooled[NF];
    const int g = blockIdx.x;
    const int tid = threadIdx.x;
    const int rg = tid / NC4;       // row group
    const int c = tid % NC4;        // float4 chunk
    const int i0 = gstart[g], i1 = gstart[g + 1];

    if (rg < 8) {
        float4 acc = make_float4(0.f, 0.f, 0.f, 0.f);
        for (int i = i0 + rg; i < i1; i += 8) {
            float4 v = ((const float4*)h)[(size_t)i * NC4 + c];
            acc.x += v.x; acc.y += v.y; acc.z += v.z; acc.w += v.w;
        }
        ((float4*)&red[rg][0])[c] = acc;
    }
    __syncthreads();

    if (tid < NF) {
        float s = 0.0f;
        #pragma unroll
        for (int r = 0; r < 8; ++r) s += red[r][tid];
        float cntg = (float)(i1 - i0);
        pooled[tid] = s / fmaxf(cntg, 1.0f);
    }
    __syncthreads();

    if (tid < ncls) {
        float a = 0.0f;
        #pragma unroll 8
        for (int f = 0; f < NF; ++f)
            a += pooled[f] * Wl[f * ncls + tid];
        out[(size_t)g * ncls + tid] = a + bl[tid];
    }
}

extern "C" void kernel_launch(void* const* d_in, const int* in_sizes, int n_in,
                              void* d_out, int out_size, void* d_ws, size_t ws_size,
                              hipStream_t stream) {
    const float* x  = (const float*)d_in[0];
    const float* ew = (const float*)d_in[1];
    const float* W1 = (const float*)d_in[2];
    const float* b1 = (const float*)d_in[3];
    const float* W2 = (const float*)d_in[4];
    const float* b2 = (const float*)d_in[5];
    const float* W3 = (const float*)d_in[6];
    const float* b3 = (const float*)d_in[7];
    const float* Wl = (const float*)d_in[8];
    const float* bl = (const float*)d_in[9];
    const int* ei    = (const int*)d_in[10];
    const int* batch = (const int*)d_in[11];

    const int n = in_sizes[0] / NF;            // 50000
    const int E = in_sizes[1];                 // 800000
    const int ncls = 10;
    const int ngraphs = out_size / ncls;       // 512
    const int* src = ei;
    const int* dst = ei + E;

    // ---- workspace layout ----
    char* p = (char*)d_ws;
    float2* epack  = (float2*)p;            p += (size_t)E * sizeof(float2);
    float* bufA    = (float*)p;             p += (size_t)n * NF * sizeof(float);
    float* bufB    = (float*)p;             p += (size_t)n * NF * sizeof(float);
    float* dis     = (float*)p;             p += (size_t)n * sizeof(float);
    int*   hist    = (int*)p;               p += (size_t)n * sizeof(int);
    int*   rowstart= (int*)p;               p += (size_t)(n + 1) * sizeof(int);
    int*   tmp     = (int*)p;               p += (size_t)n * sizeof(int);
    int*   gstart  = (int*)p;               p += (size_t)(ngraphs + 1) * sizeof(int);
    int*   blksum  = (int*)p;               p += 256 * sizeof(int);
    int*   blkoff  = (int*)p;               /* p += 256 * sizeof(int); */

    const int T = 256;
    int gN    = (n + T - 1) / T;       // also the scan block count (196 <= 256)
    int gE    = (E + T - 1) / T;
    int gN24  = (n * NC4 + T - 1) / T;
    int gGemm = (n + 31) / 32;

    // ---- build degree + CSR + graph bounds (once, reused by all layers) ----
    k_init<<<gN, T, 0, stream>>>(dis, hist, n);
    k_deg_hist<<<gE, T, 0, stream>>>(dst, ew, dis, hist, E);
    k_dis<<<gN, T, 0, stream>>>(dis, n);
    k_scan1<<<gN, T, 0, stream>>>(hist, tmp, blksum, n);
    k_scan2<<<1, T, 0, stream>>>(blksum, blkoff, gN);
    k_scan3<<<gN, T, 0, stream>>>(tmp, blkoff, rowstart, hist, n);
    k_scatter<<<gE, T, 0, stream>>>(src, dst, ew, dis, rowstart, hist, epack, E);
    k_bounds<<<gN, T, 0, stream>>>(batch, gstart, n, ngraphs);

    // ---- layer 1: x -> bufB (xw) -> bufA (h1) ----
    k_gemm<<<gGemm, T, 0, stream>>>(x, W1, bufB, n, 0);
    k_gather<<<gN24, T, 0, stream>>>(bufB, epack, rowstart, dis, b1, bufA, n);

    // ---- layer 2: relu(bufA) -> bufB -> bufA ----
    k_gemm<<<gGemm, T, 0, stream>>>(bufA, W2, bufB, n, 1);
    k_gather<<<gN24, T, 0, stream>>>(bufB, epack, rowstart, dis, b2, bufA, n);

    // ---- layer 3: relu(bufA) -> bufB -> bufA ----
    k_gemm<<<gGemm, T, 0, stream>>>(bufA, W3, bufB, n, 1);
    k_gather<<<gN24, T, 0, stream>>>(bufB, epack, rowstart, dis, b3, bufA, n);

    // ---- fused mean-pool + classifier head ----
    k_poolfinal<<<ngraphs, T, 0, stream>>>(bufA, gstart, Wl, bl, (float*)d_out, ncls);
}

// Round 4
// 353.127 us; speedup vs baseline: 9.3365x; 1.1293x over previous
//
#include <hip/hip_runtime.h>

#define NF 96
#define NC4 24   // NF / 4 float4 chunks per row

// ---------------- rank[e] = running count per dst (THE only atomic pass) ----
__global__ __launch_bounds__(256) void k_rank(const int* __restrict__ dst,
                                              int* __restrict__ cursor,
                                              int* __restrict__ rank, int E) {
    int e = blockIdx.x * 256 + threadIdx.x;
    if (e < E) rank[e] = atomicAdd(&cursor[dst[e]], 1);
}

// ---------------- scan pass 1: per-block inclusive scan of hist ----------------
__global__ __launch_bounds__(256) void k_scan1(const int* __restrict__ hist,
                                               int* __restrict__ tmp,
                                               int* __restrict__ blksum, int n) {
    __shared__ int s[256];
    int t = threadIdx.x;
    int i = blockIdx.x * 256 + t;
    int v = (i < n) ? hist[i] : 0;
    s[t] = v;
    __syncthreads();
    #pragma unroll
    for (int off = 1; off < 256; off <<= 1) {
        int x = (t >= off) ? s[t - off] : 0;
        __syncthreads();
        s[t] += x;
        __syncthreads();
    }
    if (i < n) tmp[i] = s[t];
    if (t == 255) blksum[blockIdx.x] = s[t];
}

// ---------------- scan pass 2: exclusive scan of block sums (1 block) --------
__global__ __launch_bounds__(256) void k_scan2(const int* __restrict__ blksum,
                                               int* __restrict__ blkoff, int nb) {
    __shared__ int s[256];
    int t = threadIdx.x;
    int v = (t < nb) ? blksum[t] : 0;
    s[t] = v;
    __syncthreads();
    #pragma unroll
    for (int off = 1; off < 256; off <<= 1) {
        int x = (t >= off) ? s[t - off] : 0;
        __syncthreads();
        s[t] += x;
        __syncthreads();
    }
    if (t < nb) blkoff[t] = s[t] - v;   // exclusive
}

// ---------------- scan pass 3: rowstart[i+1] = tmp[i]+blkoff ----------------
__global__ __launch_bounds__(256) void k_scan3(const int* __restrict__ tmp,
                                               const int* __restrict__ blkoff,
                                               int* __restrict__ rowstart, int n) {
    int i = blockIdx.x * 256 + threadIdx.x;
    if (i < n) {
        rowstart[i + 1] = tmp[i] + blkoff[blockIdx.x];
        if (i == 0) rowstart[0] = 0;
    }
}

// ---------------- place edges into CSR slots (no atomics) ----------------
__global__ __launch_bounds__(256) void k_place(const int* __restrict__ src,
                                               const int* __restrict__ dst,
                                               const float* __restrict__ w,
                                               const int* __restrict__ rowstart,
                                               const int* __restrict__ rank,
                                               float2* __restrict__ epack, int E) {
    int e = blockIdx.x * 256 + threadIdx.x;
    if (e < E) {
        int slot = rowstart[dst[e]] + rank[e];
        epack[slot] = make_float2(__int_as_float(src[e]), w[e]);
    }
}

// ---------------- deg from CSR row sums; dis = rsqrt(deg) ----------------
__global__ __launch_bounds__(256) void k_degdis(const float2* __restrict__ epack,
                                                const int* __restrict__ rowstart,
                                                float* __restrict__ dis, int n) {
    int i = blockIdx.x * 256 + threadIdx.x;
    if (i >= n) return;
    int j0 = rowstart[i], j1 = rowstart[i + 1];
    float deg = 1.0f;                        // self-loop weight 1
    for (int j = j0; j < j1; ++j) deg += epack[j].y;
    dis[i] = rsqrtf(deg);                    // deg >= 1 > 0 always
}

// ---------------- epack.y *= dis[src]  (fold source-side norm once) --------
__global__ __launch_bounds__(256) void k_fixnorm(float2* __restrict__ epack,
                                                 const float* __restrict__ dis, int E) {
    int j = blockIdx.x * 256 + threadIdx.x;
    if (j < E) {
        float2 ep = epack[j];
        int s = __float_as_int(ep.x);
        epack[j].y = ep.y * dis[s];
    }
}

// ---------------- graph boundaries from sorted batch ----------------
__global__ __launch_bounds__(256) void k_bounds(const int* __restrict__ batch,
                                                int* __restrict__ gstart,
                                                int n, int ngraphs) {
    int i = blockIdx.x * 256 + threadIdx.x;
    if (i >= n) return;
    int b = batch[i];
    if (i == 0) {
        for (int g = 0; g <= b; ++g) gstart[g] = 0;
    } else {
        int pb = batch[i - 1];
        for (int g = pb + 1; g <= b; ++g) gstart[g] = i;
    }
    if (i == n - 1) {
        for (int g = b + 1; g <= ngraphs; ++g) gstart[g] = n;
    }
}

// ---------------- xw = act(A) @ W   (A:[n,96], W:[96,96]) ----------------
__global__ __launch_bounds__(256) void k_gemm(const float* __restrict__ A,
                                              const float* __restrict__ W,
                                              float* __restrict__ out,
                                              int n, int relu_in) {
    __shared__ float sW[NF * NF];
    __shared__ float sA[32 * NF];
    const int tid = threadIdx.x;

    for (int i = tid; i < NF * NF; i += 256) sW[i] = W[i];

    const int row0 = blockIdx.x * 32;
    const int nrows = min(32, n - row0);

    const float4* A4 = (const float4*)A;
    float4* sA4 = (float4*)sA;
    #pragma unroll
    for (int t = 0; t < 3; ++t) {
        int id = tid + 256 * t;            // 0..767 = 32 rows * 24 chunks
        int r = id / NC4, c = id % NC4;
        if (r < nrows) {
            float4 v = A4[(size_t)(row0 + r) * NC4 + c];
            if (relu_in) {
                v.x = fmaxf(v.x, 0.0f); v.y = fmaxf(v.y, 0.0f);
                v.z = fmaxf(v.z, 0.0f); v.w = fmaxf(v.w, 0.0f);
            }
            sA4[id] = v;
        }
    }
    __syncthreads();

    const float4* sW4 = (const float4*)sW;
    float4* O4 = (float4*)out;
    #pragma unroll
    for (int t = 0; t < 3; ++t) {
        int id = tid + 256 * t;
        int r = id / NC4, c = id % NC4;
        if (r >= nrows) continue;
        float4 acc = make_float4(0.f, 0.f, 0.f, 0.f);
        #pragma unroll 8
        for (int k = 0; k < NF; ++k) {
            float a = sA[r * NF + k];
            float4 wv = sW4[k * NC4 + c];
            acc.x += a * wv.x; acc.y += a * wv.y;
            acc.z += a * wv.z; acc.w += a * wv.w;
        }
        O4[(size_t)(row0 + r) * NC4 + c] = acc;
    }
}

// ------- gather: out[i] = b + dis_i*(dis_i*xw[i] + sum_j y_j*xw[src_j]) -------
__global__ __launch_bounds__(256) void k_gather(const float* __restrict__ xw,
                                                const float2* __restrict__ epack,
                                                const int* __restrict__ rowstart,
                                                const float* __restrict__ dis,
                                                const float* __restrict__ b,
                                                float* __restrict__ out, int n) {
    int idx = blockIdx.x * 256 + threadIdx.x;   // over n * NC4
    if (idx >= n * NC4) return;
    int i = idx / NC4, c = idx % NC4;
    const float4* xw4 = (const float4*)xw;

    float di = dis[i];
    float4 v = xw4[(size_t)i * NC4 + c];
    float4 acc;
    acc.x = di * v.x;
    acc.y = di * v.y;
    acc.z = di * v.z;
    acc.w = di * v.w;

    int j0 = rowstart[i], j1 = rowstart[i + 1];
    for (int j = j0; j < j1; ++j) {
        float2 ep = epack[j];
        int s = __float_as_int(ep.x);
        float coef = ep.y;                      // w * dis[src]
        float4 sv = xw4[(size_t)s * NC4 + c];
        acc.x += coef * sv.x;
        acc.y += coef * sv.y;
        acc.z += coef * sv.z;
        acc.w += coef * sv.w;
    }
    float4 bb = ((const float4*)b)[c];
    float4 o;
    o.x = di * acc.x + bb.x;
    o.y = di * acc.y + bb.y;
    o.z = di * acc.z + bb.z;
    o.w = di * acc.w + bb.w;
    ((float4*)out)[idx] = o;
}

// ---------------- fused mean-pool + classifier head ----------------
__global__ __launch_bounds__(256) void k_poolfinal(const float* __restrict__ h,
                                                   const int* __restrict__ gstart,
                                                   const float* __restrict__ Wl,
                                                   const float* __restrict__ bl,
                                                   float* __restrict__ out, int ncls) {
    __shared__ float red[8][NF];
    __shared__ float pooled[NF];
    const int g = blockIdx.x;
    const int tid = threadIdx.x;
    const int rg = tid / NC4;       // row group
    const int c = tid % NC4;        // float4 chunk
    const int i0 = gstart[g], i1 = gstart[g + 1];

    if (rg < 8) {
        float4 acc = make_float4(0.f, 0.f, 0.f, 0.f);
        for (int i = i0 + rg; i < i1; i += 8) {
            float4 v = ((const float4*)h)[(size_t)i * NC4 + c];
            acc.x += v.x; acc.y += v.y; acc.z += v.z; acc.w += v.w;
        }
        ((float4*)&red[rg][0])[c] = acc;
    }
    __syncthreads();

    if (tid < NF) {
        float s = 0.0f;
        #pragma unroll
        for (int r = 0; r < 8; ++r) s += red[r][tid];
        float cntg = (float)(i1 - i0);
        pooled[tid] = s / fmaxf(cntg, 1.0f);
    }
    __syncthreads();

    if (tid < ncls) {
        float a = 0.0f;
        #pragma unroll 8
        for (int f = 0; f < NF; ++f)
            a += pooled[f] * Wl[f * ncls + tid];
        out[(size_t)g * ncls + tid] = a + bl[tid];
    }
}

extern "C" void kernel_launch(void* const* d_in, const int* in_sizes, int n_in,
                              void* d_out, int out_size, void* d_ws, size_t ws_size,
                              hipStream_t stream) {
    const float* x  = (const float*)d_in[0];
    const float* ew = (const float*)d_in[1];
    const float* W1 = (const float*)d_in[2];
    const float* b1 = (const float*)d_in[3];
    const float* W2 = (const float*)d_in[4];
    const float* b2 = (const float*)d_in[5];
    const float* W3 = (const float*)d_in[6];
    const float* b3 = (const float*)d_in[7];
    const float* Wl = (const float*)d_in[8];
    const float* bl = (const float*)d_in[9];
    const int* ei    = (const int*)d_in[10];
    const int* batch = (const int*)d_in[11];

    const int n = in_sizes[0] / NF;            // 50000
    const int E = in_sizes[1];                 // 800000
    const int ncls = 10;
    const int ngraphs = out_size / ncls;       // 512
    const int* src = ei;
    const int* dst = ei + E;

    // ---- workspace layout ----
    char* p = (char*)d_ws;
    float2* epack  = (float2*)p;            p += (size_t)E * sizeof(float2);
    float* bufA    = (float*)p;             p += (size_t)n * NF * sizeof(float);
    float* bufB    = (float*)p;             p += (size_t)n * NF * sizeof(float);
    int*   rank    = (int*)p;               p += (size_t)E * sizeof(int);
    float* dis     = (float*)p;             p += (size_t)n * sizeof(float);
    int*   cursor  = (int*)p;               p += (size_t)n * sizeof(int);
    int*   rowstart= (int*)p;               p += (size_t)(n + 1) * sizeof(int);
    int*   tmp     = (int*)p;               p += (size_t)n * sizeof(int);
    int*   gstart  = (int*)p;               p += (size_t)(ngraphs + 1) * sizeof(int);
    int*   blksum  = (int*)p;               p += 256 * sizeof(int);
    int*   blkoff  = (int*)p;               /* p += 256 * sizeof(int); */

    const int T = 256;
    int gN    = (n + T - 1) / T;       // scan block count (196 <= 256)
    int gE    = (E + T - 1) / T;
    int gN24  = (n * NC4 + T - 1) / T;
    int gGemm = (n + 31) / 32;

    // ---- CSR build: ONE atomic pass, deg derived from CSR ----
    hipMemsetAsync(cursor, 0, (size_t)n * sizeof(int), stream);
    k_rank<<<gE, T, 0, stream>>>(dst, cursor, rank, E);
    k_scan1<<<gN, T, 0, stream>>>(cursor, tmp, blksum, n);
    k_scan2<<<1, T, 0, stream>>>(blksum, blkoff, gN);
    k_scan3<<<gN, T, 0, stream>>>(tmp, blkoff, rowstart, n);
    k_place<<<gE, T, 0, stream>>>(src, dst, ew, rowstart, rank, epack, E);
    k_degdis<<<gN, T, 0, stream>>>(epack, rowstart, dis, n);
    k_fixnorm<<<gE, T, 0, stream>>>(epack, dis, E);
    k_bounds<<<gN, T, 0, stream>>>(batch, gstart, n, ngraphs);

    // ---- layer 1: x -> bufB (xw) -> bufA (h1) ----
    k_gemm<<<gGemm, T, 0, stream>>>(x, W1, bufB, n, 0);
    k_gather<<<gN24, T, 0, stream>>>(bufB, epack, rowstart, dis, b1, bufA, n);

    // ---- layer 2: relu(bufA) -> bufB -> bufA ----
    k_gemm<<<gGemm, T, 0, stream>>>(bufA, W2, bufB, n, 1);
    k_gather<<<gN24, T, 0, stream>>>(bufB, epack, rowstart, dis, b2, bufA, n);

    // ---- layer 3: relu(bufA) -> bufB -> bufA ----
    k_gemm<<<gGemm, T, 0, stream>>>(bufA, W3, bufB, n, 1);
    k_gather<<<gN24, T, 0, stream>>>(bufB, epack, rowstart, dis, b3, bufA, n);

    // ---- fused mean-pool + classifier head ----
    k_poolfinal<<<ngraphs, T, 0, stream>>>(bufA, gstart, Wl, bl, (float*)d_out, ncls);
}

// Round 5
// 326.969 us; speedup vs baseline: 10.0834x; 1.0800x over previous
//
#include <hip/hip_runtime.h>
#include <hip/hip_fp16.h>

#define NF 96
#define NC4 24   // NF / 4 float4 chunks per row

struct h4 { __half2 a, b; };   // 8 bytes = 4 fp16 values

// ---------------- rank[e] = running count per dst (THE only atomic pass) ----
__global__ __launch_bounds__(256) void k_rank(const int* __restrict__ dst,
                                              int* __restrict__ cursor,
                                              int* __restrict__ rank, int E) {
    int e = blockIdx.x * 256 + threadIdx.x;
    if (e < E) rank[e] = atomicAdd(&cursor[dst[e]], 1);
}

// ---------------- scan pass 1: per-block inclusive scan of hist ----------------
__global__ __launch_bounds__(256) void k_scan1(const int* __restrict__ hist,
                                               int* __restrict__ tmp,
                                               int* __restrict__ blksum, int n) {
    __shared__ int s[256];
    int t = threadIdx.x;
    int i = blockIdx.x * 256 + t;
    int v = (i < n) ? hist[i] : 0;
    s[t] = v;
    __syncthreads();
    #pragma unroll
    for (int off = 1; off < 256; off <<= 1) {
        int x = (t >= off) ? s[t - off] : 0;
        __syncthreads();
        s[t] += x;
        __syncthreads();
    }
    if (i < n) tmp[i] = s[t];
    if (t == 255) blksum[blockIdx.x] = s[t];
}

// ---------------- scan pass 2: exclusive scan of block sums (1 block) --------
__global__ __launch_bounds__(256) void k_scan2(const int* __restrict__ blksum,
                                               int* __restrict__ blkoff, int nb) {
    __shared__ int s[256];
    int t = threadIdx.x;
    int v = (t < nb) ? blksum[t] : 0;
    s[t] = v;
    __syncthreads();
    #pragma unroll
    for (int off = 1; off < 256; off <<= 1) {
        int x = (t >= off) ? s[t - off] : 0;
        __syncthreads();
        s[t] += x;
        __syncthreads();
    }
    if (t < nb) blkoff[t] = s[t] - v;   // exclusive
}

// ---------------- scan pass 3: rowstart[i+1] = tmp[i]+blkoff ----------------
__global__ __launch_bounds__(256) void k_scan3(const int* __restrict__ tmp,
                                               const int* __restrict__ blkoff,
                                               int* __restrict__ rowstart, int n) {
    int i = blockIdx.x * 256 + threadIdx.x;
    if (i < n) {
        rowstart[i + 1] = tmp[i] + blkoff[blockIdx.x];
        if (i == 0) rowstart[0] = 0;
    }
}

// ---------------- place edges into CSR slots (no atomics) ----------------
__global__ __launch_bounds__(256) void k_place(const int* __restrict__ src,
                                               const int* __restrict__ dst,
                                               const float* __restrict__ w,
                                               const int* __restrict__ rowstart,
                                               const int* __restrict__ rank,
                                               float2* __restrict__ epack, int E) {
    int e = blockIdx.x * 256 + threadIdx.x;
    if (e < E) {
        int slot = rowstart[dst[e]] + rank[e];
        epack[slot] = make_float2(__int_as_float(src[e]), w[e]);
    }
}

// ---------------- deg from CSR row sums; dis = rsqrt(deg) ----------------
__global__ __launch_bounds__(256) void k_degdis(const float2* __restrict__ epack,
                                                const int* __restrict__ rowstart,
                                                float* __restrict__ dis, int n) {
    int i = blockIdx.x * 256 + threadIdx.x;
    if (i >= n) return;
    int j0 = rowstart[i], j1 = rowstart[i + 1];
    float deg = 1.0f;                        // self-loop weight 1
    for (int j = j0; j < j1; ++j) deg += epack[j].y;
    dis[i] = rsqrtf(deg);                    // deg >= 1 > 0 always
}

// ---------------- epack.y *= dis[src]  (fold source-side norm once) --------
__global__ __launch_bounds__(256) void k_fixnorm(float2* __restrict__ epack,
                                                 const float* __restrict__ dis, int E) {
    int j = blockIdx.x * 256 + threadIdx.x;
    if (j < E) {
        float2 ep = epack[j];
        int s = __float_as_int(ep.x);
        epack[j].y = ep.y * dis[s];
    }
}

// ---------------- graph boundaries from sorted batch ----------------
__global__ __launch_bounds__(256) void k_bounds(const int* __restrict__ batch,
                                                int* __restrict__ gstart,
                                                int n, int ngraphs) {
    int i = blockIdx.x * 256 + threadIdx.x;
    if (i >= n) return;
    int b = batch[i];
    if (i == 0) {
        for (int g = 0; g <= b; ++g) gstart[g] = 0;
    } else {
        int pb = batch[i - 1];
        for (int g = pb + 1; g <= b; ++g) gstart[g] = i;
    }
    if (i == n - 1) {
        for (int g = b + 1; g <= ngraphs; ++g) gstart[g] = n;
    }
}

// ---------------- xw = act(A) @ W, output fp16  (A:[n,96] f32, W:[96,96]) ----
__global__ __launch_bounds__(256) void k_gemm(const float* __restrict__ A,
                                              const float* __restrict__ W,
                                              h4* __restrict__ out,
                                              int n, int relu_in) {
    __shared__ float sW[NF * NF];
    __shared__ float sA[32 * NF];
    const int tid = threadIdx.x;

    for (int i = tid; i < NF * NF; i += 256) sW[i] = W[i];

    const int row0 = blockIdx.x * 32;
    const int nrows = min(32, n - row0);

    const float4* A4 = (const float4*)A;
    float4* sA4 = (float4*)sA;
    #pragma unroll
    for (int t = 0; t < 3; ++t) {
        int id = tid + 256 * t;            // 0..767 = 32 rows * 24 chunks
        int r = id / NC4, c = id % NC4;
        if (r < nrows) {
            float4 v = A4[(size_t)(row0 + r) * NC4 + c];
            if (relu_in) {
                v.x = fmaxf(v.x, 0.0f); v.y = fmaxf(v.y, 0.0f);
                v.z = fmaxf(v.z, 0.0f); v.w = fmaxf(v.w, 0.0f);
            }
            sA4[id] = v;
        }
    }
    __syncthreads();

    const float4* sW4 = (const float4*)sW;
    #pragma unroll
    for (int t = 0; t < 3; ++t) {
        int id = tid + 256 * t;
        int r = id / NC4, c = id % NC4;
        if (r >= nrows) continue;
        float4 acc = make_float4(0.f, 0.f, 0.f, 0.f);
        #pragma unroll 8
        for (int k = 0; k < NF; ++k) {
            float a = sA[r * NF + k];
            float4 wv = sW4[k * NC4 + c];
            acc.x += a * wv.x; acc.y += a * wv.y;
            acc.z += a * wv.z; acc.w += a * wv.w;
        }
        h4 o;
        o.a = __floats2half2_rn(acc.x, acc.y);
        o.b = __floats2half2_rn(acc.z, acc.w);
        out[(size_t)(row0 + r) * NC4 + c] = o;
    }
}

// ------- gather: out[i] = b + dis_i*(dis_i*xw[i] + sum_j y_j*xw[src_j]) -------
// xw is fp16 (h4 chunks), accumulation in f32.
__global__ __launch_bounds__(256) void k_gather(const h4* __restrict__ xw,
                                                const float2* __restrict__ epack,
                                                const int* __restrict__ rowstart,
                                                const float* __restrict__ dis,
                                                const float* __restrict__ b,
                                                float* __restrict__ out, int n) {
    int idx = blockIdx.x * 256 + threadIdx.x;   // over n * NC4
    if (idx >= n * NC4) return;
    int i = idx / NC4, c = idx % NC4;

    float di = dis[i];
    h4 v = xw[(size_t)i * NC4 + c];
    float2 va = __half22float2(v.a), vb = __half22float2(v.b);
    float4 acc;
    acc.x = di * va.x;
    acc.y = di * va.y;
    acc.z = di * vb.x;
    acc.w = di * vb.y;

    int j0 = rowstart[i], j1 = rowstart[i + 1];
    for (int j = j0; j < j1; ++j) {
        float2 ep = epack[j];
        int s = __float_as_int(ep.x);
        float coef = ep.y;                      // w * dis[src]
        h4 sv = xw[(size_t)s * NC4 + c];
        float2 sa = __half22float2(sv.a), sb = __half22float2(sv.b);
        acc.x += coef * sa.x;
        acc.y += coef * sa.y;
        acc.z += coef * sb.x;
        acc.w += coef * sb.y;
    }
    float4 bb = ((const float4*)b)[c];
    float4 o;
    o.x = di * acc.x + bb.x;
    o.y = di * acc.y + bb.y;
    o.z = di * acc.z + bb.z;
    o.w = di * acc.w + bb.w;
    ((float4*)out)[idx] = o;
}

// ---------------- fused mean-pool + classifier head ----------------
__global__ __launch_bounds__(256) void k_poolfinal(const float* __restrict__ h,
                                                   const int* __restrict__ gstart,
                                                   const float* __restrict__ Wl,
                                                   const float* __restrict__ bl,
                                                   float* __restrict__ out, int ncls) {
    __shared__ float red[8][NF];
    __shared__ float pooled[NF];
    const int g = blockIdx.x;
    const int tid = threadIdx.x;
    const int rg = tid / NC4;       // row group
    const int c = tid % NC4;        // float4 chunk
    const int i0 = gstart[g], i1 = gstart[g + 1];

    if (rg < 8) {
        float4 acc = make_float4(0.f, 0.f, 0.f, 0.f);
        for (int i = i0 + rg; i < i1; i += 8) {
            float4 v = ((const float4*)h)[(size_t)i * NC4 + c];
            acc.x += v.x; acc.y += v.y; acc.z += v.z; acc.w += v.w;
        }
        ((float4*)&red[rg][0])[c] = acc;
    }
    __syncthreads();

    if (tid < NF) {
        float s = 0.0f;
        #pragma unroll
        for (int r = 0; r < 8; ++r) s += red[r][tid];
        float cntg = (float)(i1 - i0);
        pooled[tid] = s / fmaxf(cntg, 1.0f);
    }
    __syncthreads();

    if (tid < ncls) {
        float a = 0.0f;
        #pragma unroll 8
        for (int f = 0; f < NF; ++f)
            a += pooled[f] * Wl[f * ncls + tid];
        out[(size_t)g * ncls + tid] = a + bl[tid];
    }
}

extern "C" void kernel_launch(void* const* d_in, const int* in_sizes, int n_in,
                              void* d_out, int out_size, void* d_ws, size_t ws_size,
                              hipStream_t stream) {
    const float* x  = (const float*)d_in[0];
    const float* ew = (const float*)d_in[1];
    const float* W1 = (const float*)d_in[2];
    const float* b1 = (const float*)d_in[3];
    const float* W2 = (const float*)d_in[4];
    const float* b2 = (const float*)d_in[5];
    const float* W3 = (const float*)d_in[6];
    const float* b3 = (const float*)d_in[7];
    const float* Wl = (const float*)d_in[8];
    const float* bl = (const float*)d_in[9];
    const int* ei    = (const int*)d_in[10];
    const int* batch = (const int*)d_in[11];

    const int n = in_sizes[0] / NF;            // 50000
    const int E = in_sizes[1];                 // 800000
    const int ncls = 10;
    const int ngraphs = out_size / ncls;       // 512
    const int* src = ei;
    const int* dst = ei + E;

    // ---- workspace layout ----
    char* p = (char*)d_ws;
    float2* epack  = (float2*)p;            p += (size_t)E * sizeof(float2);
    float* bufA    = (float*)p;             p += (size_t)n * NF * sizeof(float);
    h4*    bufB    = (h4*)p;                p += (size_t)n * NC4 * sizeof(h4);   // fp16 xw
    int*   rank    = (int*)p;               p += (size_t)E * sizeof(int);
    float* dis     = (float*)p;             p += (size_t)n * sizeof(float);
    int*   cursor  = (int*)p;               p += (size_t)n * sizeof(int);
    int*   rowstart= (int*)p;               p += (size_t)(n + 1) * sizeof(int);
    int*   tmp     = (int*)p;               p += (size_t)n * sizeof(int);
    int*   gstart  = (int*)p;               p += (size_t)(ngraphs + 1) * sizeof(int);
    int*   blksum  = (int*)p;               p += 256 * sizeof(int);
    int*   blkoff  = (int*)p;               /* p += 256 * sizeof(int); */

    const int T = 256;
    int gN    = (n + T - 1) / T;       // scan block count (196 <= 256)
    int gE    = (E + T - 1) / T;
    int gN24  = (n * NC4 + T - 1) / T;
    int gGemm = (n + 31) / 32;

    // ---- CSR build: ONE atomic pass, deg derived from CSR ----
    hipMemsetAsync(cursor, 0, (size_t)n * sizeof(int), stream);
    k_rank<<<gE, T, 0, stream>>>(dst, cursor, rank, E);
    k_scan1<<<gN, T, 0, stream>>>(cursor, tmp, blksum, n);
    k_scan2<<<1, T, 0, stream>>>(blksum, blkoff, gN);
    k_scan3<<<gN, T, 0, stream>>>(tmp, blkoff, rowstart, n);
    k_place<<<gE, T, 0, stream>>>(src, dst, ew, rowstart, rank, epack, E);
    k_degdis<<<gN, T, 0, stream>>>(epack, rowstart, dis, n);
    k_fixnorm<<<gE, T, 0, stream>>>(epack, dis, E);
    k_bounds<<<gN, T, 0, stream>>>(batch, gstart, n, ngraphs);

    // ---- layer 1: x -> bufB (xw fp16) -> bufA (h1 f32) ----
    k_gemm<<<gGemm, T, 0, stream>>>(x, W1, bufB, n, 0);
    k_gather<<<gN24, T, 0, stream>>>(bufB, epack, rowstart, dis, b1, bufA, n);

    // ---- layer 2: relu(bufA) -> bufB -> bufA ----
    k_gemm<<<gGemm, T, 0, stream>>>(bufA, W2, bufB, n, 1);
    k_gather<<<gN24, T, 0, stream>>>(bufB, epack, rowstart, dis, b2, bufA, n);

    // ---- layer 3: relu(bufA) -> bufB -> bufA ----
    k_gemm<<<gGemm, T, 0, stream>>>(bufA, W3, bufB, n, 1);
    k_gather<<<gN24, T, 0, stream>>>(bufB, epack, rowstart, dis, b3, bufA, n);

    // ---- fused mean-pool + classifier head ----
    k_poolfinal<<<ngraphs, T, 0, stream>>>(bufA, gstart, Wl, bl, (float*)d_out, ncls);
}